// Round 5
// baseline (192.632 us; speedup 1.0000x reference)
//
#include <hip/hip_runtime.h>

// StandardAttention: B=2,S=2048,D=1024,H=16,DQK=DV=64. fp32 in/out, bf16 MFMA inside.
// Workspace layout (56 MB):
//   xb  [4096][1024] bf16           8 MB
//   WT  [4][1024][1024] bf16 (W^T)  8 MB
//   Q,K [B][H][S][64] bf16          16 MB   (Q pre-scaled by 0.125*log2(e))
//   (unused slot)                   8 MB
//   Vp  [B][H][64][S] bf16          8 MB    (V^T with per-32 column permute, written by GEMM)
//   AO  [B][S][1024] bf16           8 MB
//
// R1: runtime-cur dbuf in GEMMs regressed (VALU 3x) -> reverted.
// R2: BK=64 single-buffer GEMM loops -> gemm_qkv off the top-5.
// R3/R4: flash 128-row 8-wave blocks -> NEUTRAL (49 us). Post-mortem: heavy/light
//   assignment by blk parity aliases with XCD round-robin (XCD = blk&7): even XCDs
//   got ONLY heavy blocks (73.5% of work on half the machine) -> occupancy stuck 22%.
// R5: round-based XCD-BALANCED schedule: round r = blk>>3 -> all 8 blocks of a round
//   (one per XCD) share qi = 15-(r&15); bh = (r>>4)*8 | (blk&7). Per-XCD work identical
//   by construction; heavy rounds launch first (light blocks fill the drain tail).

typedef float  f32x4  __attribute__((ext_vector_type(4)));
typedef __bf16 bf16x8 __attribute__((ext_vector_type(8)));

__device__ __forceinline__ unsigned short f2bf(float f) {
    __bf16 h = (__bf16)f;
    return __builtin_bit_cast(unsigned short, h);
}

// async global->LDS, 16B per lane; lds base wave-uniform (HW: base + lane*16)
__device__ __forceinline__ void gld16(unsigned short* lds, const unsigned short* g) {
    __builtin_amdgcn_global_load_lds(
        (const __attribute__((address_space(1))) void*)g,
        (__attribute__((address_space(3))) void*)lds, 16, 0, 0);
}

// ---------------- cast x -> bf16 ----------------
__global__ __launch_bounds__(256) void castx(const float* __restrict__ x,
                                             unsigned short* __restrict__ xb) {
    size_t i = ((size_t)blockIdx.x * 256 + threadIdx.x) * 4;
    float4 v = *(const float4*)(x + i);
    ushort4 o;
    o.x = f2bf(v.x); o.y = f2bf(v.y); o.z = f2bf(v.z); o.w = f2bf(v.w);
    *(ushort4*)(xb + i) = o;
}

// ---------------- transpose+cast weights: W[1024][1024] f32 -> WT[z][1024][1024] bf16 ----
__global__ __launch_bounds__(256) void wtrans(const float* __restrict__ W0,
                                              const float* __restrict__ W1,
                                              const float* __restrict__ W2,
                                              const float* __restrict__ W3,
                                              unsigned short* __restrict__ WT) {
    __shared__ float T[64][65];
    const int z = blockIdx.z;
    const float* W = (z == 0) ? W0 : (z == 1) ? W1 : (z == 2) ? W2 : W3;
    const int k0 = blockIdx.y * 64, n0 = blockIdx.x * 64;
    const int tid = threadIdx.x;
#pragma unroll
    for (int i = 0; i < 4; i++) {
        int c = tid + i * 256;
        int r = c >> 4, col = (c & 15) * 4;
        float4 v = *(const float4*)(W + (size_t)(k0 + r) * 1024 + n0 + col);
        T[r][col] = v.x; T[r][col + 1] = v.y; T[r][col + 2] = v.z; T[r][col + 3] = v.w;
    }
    __syncthreads();
    unsigned short* out = WT + (size_t)z * 1024 * 1024;
#pragma unroll
    for (int i = 0; i < 2; i++) {
        int c = tid + i * 256;
        int nr = c >> 3, koff = (c & 7) * 8;
        union { unsigned short us[8]; uint4 v; } pk;
#pragma unroll
        for (int j = 0; j < 8; j++) pk.us[j] = f2bf(T[koff + j][nr]);
        *(uint4*)(out + (size_t)(n0 + nr) * 1024 + k0 + koff) = pk.v;
    }
}

// ---------------- QKV GEMM: [4096][1024] x WT^T per z; BK=64, XCD-swizzled grid --------
// Flat grid 768. Decode keeps all 8 n-blocks of a (z,m) A-tile on ONE XCD, consecutive
// groups on an XCD share z -> working set ~3 MB < 4 MB/XCD L2.
// K-loop: BK=64, single-buffered [128][64] LDS tiles (flash-geometry XOR chunk swizzle),
// 2 barriers + 8 gld16 + 16 ds_read_b128 + 32 MFMA per step, 16 steps.
// z=0 (Q, scaled) / z=1 (K): operand-SWAPPED mfma -> ushort4 stores into [B][H][S][64].
// z=2 (V): normal orientation -> reg quad = one Vp permute group -> ushort4 into Vp.
__global__ __launch_bounds__(256) void gemm_qkv(const unsigned short* __restrict__ A,
                                                const unsigned short* __restrict__ WTall,
                                                unsigned short* __restrict__ outq,
                                                unsigned short* __restrict__ Vp) {
    __shared__ unsigned short As[128 * 64];
    __shared__ unsigned short Bs[128 * 64];
    const int tid = threadIdx.x;
    const int w = tid >> 6, lane = tid & 63, quad = lane >> 4, ln = lane & 15;

    const int blk = blockIdx.x;
    const int n0 = ((blk >> 3) & 7) * 128;
    const int g  = ((blk >> 6) << 3) | (blk & 7);   // 0..95 = z*32+m
    const int z  = g >> 5;
    const int m0 = (g & 31) * 128;

    const unsigned short* BT = WTall + (size_t)z * (1024 * 1024);
    const float scl = (z == 0) ? 0.180336878f : 1.0f;
    const bool swp = (z < 2);

    const int lr8 = lane >> 3;                      // row within 8-row staging group
    const int lc8 = ((lane & 7) ^ lr8) * 8;         // XOR-swizzled source chunk (elems)
    const int fsw = (quad ^ (ln & 7)) * 8;          // swizzled frag-read chunk (elems)

    const f32x4 z4 = {0.f, 0.f, 0.f, 0.f};
    f32x4 acc[4][4];
#pragma unroll
    for (int i = 0; i < 4; i++)
#pragma unroll
        for (int j = 0; j < 4; j++) acc[i][j] = z4;

    const int wm = (w & 1) * 64, wn = (w >> 1) * 64;
    const int Rb = w * 32;                          // staging row base for this wave

    for (int k0 = 0; k0 < 1024; k0 += 64) {
        __syncthreads();
#pragma unroll
        for (int s = 0; s < 4; s++) {
            gld16(As + (Rb + s * 8) * 64, A  + (size_t)(m0 + Rb + s * 8 + lr8) * 1024 + k0 + lc8);
            gld16(Bs + (Rb + s * 8) * 64, BT + (size_t)(n0 + Rb + s * 8 + lr8) * 1024 + k0 + lc8);
        }
        __syncthreads();
#pragma unroll
        for (int ks = 0; ks < 2; ks++) {
            const int co = fsw ^ (ks * 32);         // elem offset: chunk quad (+4 for ks=1)
            bf16x8 af[4], bfr[4];
#pragma unroll
            for (int t = 0; t < 4; t++)
                af[t] = *(const bf16x8*)&As[(wm + t * 16 + ln) * 64 + co];
#pragma unroll
            for (int t = 0; t < 4; t++)
                bfr[t] = *(const bf16x8*)&Bs[(wn + t * 16 + ln) * 64 + co];
            if (swp) {
#pragma unroll
                for (int tm = 0; tm < 4; tm++)
#pragma unroll
                    for (int tn = 0; tn < 4; tn++)
                        acc[tm][tn] = __builtin_amdgcn_mfma_f32_16x16x32_bf16(
                            bfr[tn], af[tm], acc[tm][tn], 0, 0, 0);
            } else {
#pragma unroll
                for (int tm = 0; tm < 4; tm++)
#pragma unroll
                    for (int tn = 0; tn < 4; tn++)
                        acc[tm][tn] = __builtin_amdgcn_mfma_f32_16x16x32_bf16(
                            af[tm], bfr[tn], acc[tm][tn], 0, 0, 0);
            }
        }
    }

    if (swp) {
        // acc[tm][tn] = D^T block: lane ln -> s-row, regs -> 4 consecutive d
#pragma unroll
        for (int tm = 0; tm < 4; tm++)
#pragma unroll
            for (int tn = 0; tn < 4; tn++) {
                int mg = m0 + wm + tm * 16 + ln;            // s row (global among 4096)
                int nb = n0 + wn + tn * 16 + quad * 4;      // d col base
                int b = mg >> 11, s = mg & 2047, h = nb >> 6, dd = nb & 63;
                ushort4 o;
                o.x = f2bf(acc[tm][tn][0] * scl);
                o.y = f2bf(acc[tm][tn][1] * scl);
                o.z = f2bf(acc[tm][tn][2] * scl);
                o.w = f2bf(acc[tm][tn][3] * scl);
                size_t zoff = (size_t)z * (4096 * 1024);
                *(ushort4*)(outq + zoff + (((size_t)(b * 16 + h) * 2048 + s) << 6) + dd) = o;
            }
    } else {
        // V: normal D block: lane ln -> d, regs -> 4 consecutive s = one Vp permute group
#pragma unroll
        for (int tm = 0; tm < 4; tm++)
#pragma unroll
            for (int tn = 0; tn < 4; tn++) {
                int mg = m0 + wm + tm * 16 + quad * 4;      // s base (r spans 4)
                int ng = n0 + wn + tn * 16 + ln;            // d
                int b = mg >> 11, h = ng >> 6, dd = ng & 63;
                int sblk = (mg & 2047) & ~63;
                int cb = tm >> 1, t16 = tm & 1;
                int pp = cb * 32 + quad * 8 + t16 * 4;
                ushort4 o;
                o.x = f2bf(acc[tm][tn][0]);
                o.y = f2bf(acc[tm][tn][1]);
                o.z = f2bf(acc[tm][tn][2]);
                o.w = f2bf(acc[tm][tn][3]);
                *(ushort4*)(Vp + ((size_t)(b * 16 + h) * 64 + dd) * 2048 + sblk + pp) = o;
            }
    }
}

// ---------------- out-proj GEMM: out[4096][1024] = AO @ WoT^T, 128x128, XCD-swizzled ----
// Flat grid 256; all 8 n-blocks of an A m-tile on one XCD. Swapped mfma -> float4 stores.
// BK=64 single-buffer loop (1 block/CU -> every barrier drain fully exposed; halving
// drain count matters most here).
__global__ __launch_bounds__(256) void gemm_o(const unsigned short* __restrict__ A,
                                              const unsigned short* __restrict__ BT,
                                              float* __restrict__ outf) {
    __shared__ unsigned short As[128 * 64];
    __shared__ unsigned short Bs[128 * 64];
    const int tid = threadIdx.x;
    const int w = tid >> 6, lane = tid & 63, quad = lane >> 4, ln = lane & 15;

    const int blk = blockIdx.x;
    const int n0 = ((blk >> 3) & 7) * 128;
    const int m0 = (((blk >> 6) << 3) | (blk & 7)) * 128;   // 0..31 tiles

    const int lr8 = lane >> 3;
    const int lc8 = ((lane & 7) ^ lr8) * 8;
    const int fsw = (quad ^ (ln & 7)) * 8;

    const f32x4 z4 = {0.f, 0.f, 0.f, 0.f};
    f32x4 acc[4][4];
#pragma unroll
    for (int i = 0; i < 4; i++)
#pragma unroll
        for (int j = 0; j < 4; j++) acc[i][j] = z4;

    const int wm = (w & 1) * 64, wn = (w >> 1) * 64;
    const int Rb = w * 32;

    for (int k0 = 0; k0 < 1024; k0 += 64) {
        __syncthreads();
#pragma unroll
        for (int s = 0; s < 4; s++) {
            gld16(As + (Rb + s * 8) * 64, A  + (size_t)(m0 + Rb + s * 8 + lr8) * 1024 + k0 + lc8);
            gld16(Bs + (Rb + s * 8) * 64, BT + (size_t)(n0 + Rb + s * 8 + lr8) * 1024 + k0 + lc8);
        }
        __syncthreads();
#pragma unroll
        for (int ks = 0; ks < 2; ks++) {
            const int co = fsw ^ (ks * 32);
            bf16x8 af[4], bfr[4];
#pragma unroll
            for (int t = 0; t < 4; t++)
                af[t] = *(const bf16x8*)&As[(wm + t * 16 + ln) * 64 + co];
#pragma unroll
            for (int t = 0; t < 4; t++)
                bfr[t] = *(const bf16x8*)&Bs[(wn + t * 16 + ln) * 64 + co];
#pragma unroll
            for (int tm = 0; tm < 4; tm++)
#pragma unroll
                for (int tn = 0; tn < 4; tn++)
                    acc[tm][tn] = __builtin_amdgcn_mfma_f32_16x16x32_bf16(
                        bfr[tn], af[tm], acc[tm][tn], 0, 0, 0);
        }
    }

    // D^T blocks: lane ln -> output row, reg quad -> 4 consecutive cols -> float4 stores
#pragma unroll
    for (int tm = 0; tm < 4; tm++)
#pragma unroll
        for (int tn = 0; tn < 4; tn++) {
            int mg = m0 + wm + tm * 16 + ln;
            int nb = n0 + wn + tn * 16 + quad * 4;
            *(f32x4*)(outf + (size_t)mg * 1024 + nb) = acc[tm][tn];
        }
}

// ---------------- flash attention (128 q-rows/block, 8 waves, XCD-balanced rounds) ------
// 8 waves x 16 q-rows, 64-col k-tiles, grid 512. Round-based decode: round r = blk>>3
// gives all 8 blocks of a round (one per XCD, XCD = blk&7) the SAME qi -> per-XCD work
// identical by construction. qi = 15-(r&15): heavy rounds first, light rounds drain.
// bh = (r>>4)*8 | (blk&7). Bijective over (bh,qi).
// K/V staging double-buffered, ONE barrier per tile:
//   barrier (publishes cur) -> issue gld16 for k+1 into cur^1 -> compute(cur)
// Each wave stages 8 K-rows + 8 Vp-rows (2 gld16). XOR chunk swizzle (conflict-free).
// S^T = K Q^T keeps P in the PV B-fragment registers (permutation baked into Vp).
// Fixed-shift softmax, raw v_exp. PV skipped when whole tile is masked (wave-uniform).
__global__ __launch_bounds__(512, 4) void flash(const unsigned short* __restrict__ Qb,
                                                const unsigned short* __restrict__ Kb,
                                                const unsigned short* __restrict__ Vpb,
                                                unsigned short* __restrict__ AO) {
    __shared__ __align__(16) unsigned short Ks[2][64 * 64];
    __shared__ __align__(16) unsigned short Vs[2][64 * 64];
    const int tid = threadIdx.x, w = tid >> 6, lane = tid & 63;
    const int qd = lane >> 4, ln = lane & 15;
    const int lr = lane >> 3;                  // row-within-8 for staging
    const int lchunk = (lane & 7) ^ lr;        // swizzled source 16B-chunk
    const int psw = (qd ^ (ln & 7)) * 8;       // swizzled read chunk offset (elems)

    const int blk = blockIdx.x;
    const int r  = blk >> 3;                         // round 0..63 (8 blocks = 1 per XCD)
    const int qi = 15 - (r & 15);                    // uniform within round, heavy first
    const int bh = ((r >> 4) << 3) | (blk & 7);      // 0..31
    const int qt0 = qi * 128;

    const unsigned short* Kg = Kb  + (size_t)bh * 2048 * 64;
    const unsigned short* Vg = Vpb + (size_t)bh * 64 * 2048;

    // Q fragment (B-operand of S^T MFMA): lane ln holds Q[qt0+w*16+ln][qd*8+jj]
    bf16x8 aq[2];
    {
        const unsigned short* Qrow = Qb + ((size_t)bh * 2048 + qt0 + w * 16 + ln) * 64 + qd * 8;
        aq[0] = *(const bf16x8*)(Qrow);
        aq[1] = *(const bf16x8*)(Qrow + 32);
    }

    const f32x4 z4 = {0.f, 0.f, 0.f, 0.f};
    f32x4 Oc[4];
#pragma unroll
    for (int td = 0; td < 4; td++) Oc[td] = z4;
    float lsum = 0.f;

    const int qrow = qt0 + w * 16 + ln;   // lane's q row (S^T: q indexed by ln)
    const int qmin = qt0 + w * 16;
    const int qmax = qmin + 15;
    const int kend = qt0 + 128;

    // stage(buf, kk): wave w fills K rows [w*8,w*8+8) and Vp d-rows [w*8,w*8+8)
#define FLASH_STAGE(buf, kk)                                                          \
    {                                                                                 \
        const unsigned short* kg = Kg + (size_t)((kk) + w * 8 + lr) * 64 + lchunk * 8; \
        gld16(&Ks[buf][(w * 8) * 64], kg);                                            \
        const unsigned short* vg = Vg + (size_t)(w * 8 + lr) * 2048 + (kk) + lchunk * 8; \
        gld16(&Vs[buf][(w * 8) * 64], vg);                                            \
    }

    FLASH_STAGE(0, 0);
    int cur = 0;

    for (int k0 = 0; k0 < kend; k0 += 64) {
        __syncthreads();                    // publishes buf cur (drains staging vmcnt)
        if (k0 + 64 < kend) FLASH_STAGE(cur ^ 1, k0 + 64);

        if (k0 <= qmax) {                   // wave-uniform: tile contributes for this wave
            // S^T = K Q^T : output lane (qd,ln) reg r = S[q=ln][kk = t*16 + qd*4 + r]
            f32x4 sc[4];
#pragma unroll
            for (int t = 0; t < 4; t++) {
                sc[t] = z4;
                if (k0 + t * 16 <= qmax) {
                    int off = (t * 16 + ln) * 64 + psw;
                    bf16x8 bk0 = *(const bf16x8*)&Ks[cur][off];
                    bf16x8 bk1 = *(const bf16x8*)&Ks[cur][off ^ 32];
                    sc[t] = __builtin_amdgcn_mfma_f32_16x16x32_bf16(bk0, aq[0], sc[t], 0, 0, 0);
                    sc[t] = __builtin_amdgcn_mfma_f32_16x16x32_bf16(bk1, aq[1], sc[t], 0, 0, 0);
                }
            }

            // P = exp2(S) (fixed shift), causal mask only in crossing band; pack bf16x2
            unsigned int pk[4][2];
#pragma unroll
            for (int t = 0; t < 4; t++) {
                if (k0 + t * 16 > qmax) { pk[t][0] = 0u; pk[t][1] = 0u; continue; }
                float e[4];
#pragma unroll
                for (int r2 = 0; r2 < 4; r2++) e[r2] = __builtin_amdgcn_exp2f(sc[t][r2]);
                if (k0 + t * 16 + 15 > qmin) {
#pragma unroll
                    for (int r2 = 0; r2 < 4; r2++)
                        if (k0 + t * 16 + qd * 4 + r2 > qrow) e[r2] = 0.f;
                }
                lsum += (e[0] + e[1]) + (e[2] + e[3]);
                pk[t][0] = (unsigned int)f2bf(e[0]) | ((unsigned int)f2bf(e[1]) << 16);
                pk[t][1] = (unsigned int)f2bf(e[2]) | ((unsigned int)f2bf(e[3]) << 16);
            }

            // O^T += V^T P^T under permuted contraction: B-frag(c) = own regs pk[2c..2c+1]
            union { unsigned int u[4]; bf16x8 v; } apu0, apu1;
            apu0.u[0] = pk[0][0]; apu0.u[1] = pk[0][1]; apu0.u[2] = pk[1][0]; apu0.u[3] = pk[1][1];
            apu1.u[0] = pk[2][0]; apu1.u[1] = pk[2][1]; apu1.u[2] = pk[3][0]; apu1.u[3] = pk[3][1];
#pragma unroll
            for (int td = 0; td < 4; td++) {
                int voff = (td * 16 + ln) * 64 + psw;
                bf16x8 av0 = *(const bf16x8*)&Vs[cur][voff];
                bf16x8 av1 = *(const bf16x8*)&Vs[cur][voff ^ 32];
                Oc[td] = __builtin_amdgcn_mfma_f32_16x16x32_bf16(av0, apu0.v, Oc[td], 0, 0, 0);
                Oc[td] = __builtin_amdgcn_mfma_f32_16x16x32_bf16(av1, apu1.v, Oc[td], 0, 0, 0);
            }
        }
        cur ^= 1;
    }
#undef FLASH_STAGE

    // row-sum butterfly across quads (lanes ln, ln+16, ln+32, ln+48 hold partials)
    lsum += __shfl_xor(lsum, 16);
    lsum += __shfl_xor(lsum, 32);
    const float inv = 1.0f / lsum;

    // O^T output: lane (qd,ln) reg (td,r) = O[q=ln][d = td*16 + qd*4 + r]
    const int bz = bh >> 4, h = bh & 15;
    const int rowg = qt0 + w * 16 + ln;
    unsigned short* aorow = AO + ((size_t)(bz * 2048 + rowg) << 10) + h * 64 + qd * 4;
#pragma unroll
    for (int td = 0; td < 4; td++) {
        ushort4 o;
        o.x = f2bf(Oc[td][0] * inv);
        o.y = f2bf(Oc[td][1] * inv);
        o.z = f2bf(Oc[td][2] * inv);
        o.w = f2bf(Oc[td][3] * inv);
        *(ushort4*)(aorow + td * 16) = o;
    }
}

extern "C" void kernel_launch(void* const* d_in, const int* in_sizes, int n_in,
                              void* d_out, int out_size, void* d_ws, size_t ws_size,
                              hipStream_t stream) {
    const float* x  = (const float*)d_in[0];
    const float* Wq = (const float*)d_in[1];
    const float* Wk = (const float*)d_in[2];
    const float* Wv = (const float*)d_in[3];
    const float* Wo = (const float*)d_in[4];
    float* out = (float*)d_out;

    unsigned short* xb  = (unsigned short*)d_ws;           // 4096*1024
    unsigned short* WT  = xb  + (size_t)4096 * 1024;       // 4*1024*1024
    unsigned short* Qb  = WT  + (size_t)4 * 1024 * 1024;   // Q,K contiguous ([B][H][S][64])
    unsigned short* Kb  = Qb  + (size_t)4096 * 1024;
    unsigned short* Vb  = Kb  + (size_t)4096 * 1024;       // unused (kept for layout stability)
    unsigned short* Vpb = Vb  + (size_t)4096 * 1024;       // Vp [B][H][64][S] permuted
    unsigned short* AO  = Vpb + (size_t)4096 * 1024;

    castx<<<4096, 256, 0, stream>>>(x, xb);
    wtrans<<<dim3(16, 16, 4), 256, 0, stream>>>(Wq, Wk, Wv, Wo, WT);
    gemm_qkv<<<dim3(768), 256, 0, stream>>>(xb, WT, Qb, Vpb);
    flash<<<dim3(512), 512, 0, stream>>>(Qb, Kb, Vpb, AO);
    gemm_o<<<dim3(256), 256, 0, stream>>>(AO, WT + (size_t)3 * 1024 * 1024, out);
}

// Round 6
// 188.743 us; speedup vs baseline: 1.0206x; 1.0206x over previous
//
#include <hip/hip_runtime.h>

// StandardAttention: B=2,S=2048,D=1024,H=16,DQK=DV=64. fp32 in/out, bf16 MFMA inside.
// Workspace layout (56 MB):
//   xb  [4096][1024] bf16           8 MB
//   WT  [4][1024][1024] bf16 (W^T)  8 MB
//   Q,K [B][H][S][64] bf16          16 MB   (Q pre-scaled by 0.125*log2(e))
//   (unused slot)                   8 MB
//   Vp  [B][H][64][S] bf16          8 MB    (V^T with per-32 column permute, written by GEMM)
//   AO  [B][S][1024] bf16           8 MB
//
// R1: runtime-cur dbuf in GEMMs regressed (VALU 3x) -> reverted.
// R2: BK=64 single-buffer GEMM loops -> gemm_qkv off the top-5.
// R3/R4: flash 128-row 8-wave blocks -> neutral; R5 round-schedule -> regressed.
// Post-mortem (R5): with grid 512 all blocks are CO-RESIDENT (2/CU) -> launch order
//   irrelevant; per-CU imbalance is destiny. CU c gets blk c and c+256. Imbalance
//   ratio model fits R2/R4/R5 (1.58/1.65/1.88 -> 47.9/49.2/51.8 us).
// R6: COMPLEMENTARY PAIRING by construction: blk<256 -> (bh=blk>>3, qi=blk&7);
//   blk>=256 -> same bh, qi=15-(blk&7). CU c's two blocks' qi sum to 15 ->
//   every CU gets exactly 34 k-tiles (ratio 1.00). XCDs balanced too.

typedef float  f32x4  __attribute__((ext_vector_type(4)));
typedef __bf16 bf16x8 __attribute__((ext_vector_type(8)));

__device__ __forceinline__ unsigned short f2bf(float f) {
    __bf16 h = (__bf16)f;
    return __builtin_bit_cast(unsigned short, h);
}

// async global->LDS, 16B per lane; lds base wave-uniform (HW: base + lane*16)
__device__ __forceinline__ void gld16(unsigned short* lds, const unsigned short* g) {
    __builtin_amdgcn_global_load_lds(
        (const __attribute__((address_space(1))) void*)g,
        (__attribute__((address_space(3))) void*)lds, 16, 0, 0);
}

// ---------------- cast x -> bf16 ----------------
__global__ __launch_bounds__(256) void castx(const float* __restrict__ x,
                                             unsigned short* __restrict__ xb) {
    size_t i = ((size_t)blockIdx.x * 256 + threadIdx.x) * 4;
    float4 v = *(const float4*)(x + i);
    ushort4 o;
    o.x = f2bf(v.x); o.y = f2bf(v.y); o.z = f2bf(v.z); o.w = f2bf(v.w);
    *(ushort4*)(xb + i) = o;
}

// ---------------- transpose+cast weights: W[1024][1024] f32 -> WT[z][1024][1024] bf16 ----
__global__ __launch_bounds__(256) void wtrans(const float* __restrict__ W0,
                                              const float* __restrict__ W1,
                                              const float* __restrict__ W2,
                                              const float* __restrict__ W3,
                                              unsigned short* __restrict__ WT) {
    __shared__ float T[64][65];
    const int z = blockIdx.z;
    const float* W = (z == 0) ? W0 : (z == 1) ? W1 : (z == 2) ? W2 : W3;
    const int k0 = blockIdx.y * 64, n0 = blockIdx.x * 64;
    const int tid = threadIdx.x;
#pragma unroll
    for (int i = 0; i < 4; i++) {
        int c = tid + i * 256;
        int r = c >> 4, col = (c & 15) * 4;
        float4 v = *(const float4*)(W + (size_t)(k0 + r) * 1024 + n0 + col);
        T[r][col] = v.x; T[r][col + 1] = v.y; T[r][col + 2] = v.z; T[r][col + 3] = v.w;
    }
    __syncthreads();
    unsigned short* out = WT + (size_t)z * 1024 * 1024;
#pragma unroll
    for (int i = 0; i < 2; i++) {
        int c = tid + i * 256;
        int nr = c >> 3, koff = (c & 7) * 8;
        union { unsigned short us[8]; uint4 v; } pk;
#pragma unroll
        for (int j = 0; j < 8; j++) pk.us[j] = f2bf(T[koff + j][nr]);
        *(uint4*)(out + (size_t)(n0 + nr) * 1024 + k0 + koff) = pk.v;
    }
}

// ---------------- QKV GEMM: [4096][1024] x WT^T per z; BK=64, XCD-swizzled grid --------
// Flat grid 768. Decode keeps all 8 n-blocks of a (z,m) A-tile on ONE XCD, consecutive
// groups on an XCD share z -> working set ~3 MB < 4 MB/XCD L2.
// K-loop: BK=64, single-buffered [128][64] LDS tiles (flash-geometry XOR chunk swizzle),
// 2 barriers + 8 gld16 + 16 ds_read_b128 + 32 MFMA per step, 16 steps.
// z=0 (Q, scaled) / z=1 (K): operand-SWAPPED mfma -> ushort4 stores into [B][H][S][64].
// z=2 (V): normal orientation -> reg quad = one Vp permute group -> ushort4 into Vp.
__global__ __launch_bounds__(256) void gemm_qkv(const unsigned short* __restrict__ A,
                                                const unsigned short* __restrict__ WTall,
                                                unsigned short* __restrict__ outq,
                                                unsigned short* __restrict__ Vp) {
    __shared__ unsigned short As[128 * 64];
    __shared__ unsigned short Bs[128 * 64];
    const int tid = threadIdx.x;
    const int w = tid >> 6, lane = tid & 63, quad = lane >> 4, ln = lane & 15;

    const int blk = blockIdx.x;
    const int n0 = ((blk >> 3) & 7) * 128;
    const int g  = ((blk >> 6) << 3) | (blk & 7);   // 0..95 = z*32+m
    const int z  = g >> 5;
    const int m0 = (g & 31) * 128;

    const unsigned short* BT = WTall + (size_t)z * (1024 * 1024);
    const float scl = (z == 0) ? 0.180336878f : 1.0f;
    const bool swp = (z < 2);

    const int lr8 = lane >> 3;                      // row within 8-row staging group
    const int lc8 = ((lane & 7) ^ lr8) * 8;         // XOR-swizzled source chunk (elems)
    const int fsw = (quad ^ (ln & 7)) * 8;          // swizzled frag-read chunk (elems)

    const f32x4 z4 = {0.f, 0.f, 0.f, 0.f};
    f32x4 acc[4][4];
#pragma unroll
    for (int i = 0; i < 4; i++)
#pragma unroll
        for (int j = 0; j < 4; j++) acc[i][j] = z4;

    const int wm = (w & 1) * 64, wn = (w >> 1) * 64;
    const int Rb = w * 32;                          // staging row base for this wave

    for (int k0 = 0; k0 < 1024; k0 += 64) {
        __syncthreads();
#pragma unroll
        for (int s = 0; s < 4; s++) {
            gld16(As + (Rb + s * 8) * 64, A  + (size_t)(m0 + Rb + s * 8 + lr8) * 1024 + k0 + lc8);
            gld16(Bs + (Rb + s * 8) * 64, BT + (size_t)(n0 + Rb + s * 8 + lr8) * 1024 + k0 + lc8);
        }
        __syncthreads();
#pragma unroll
        for (int ks = 0; ks < 2; ks++) {
            const int co = fsw ^ (ks * 32);         // elem offset: chunk quad (+4 for ks=1)
            bf16x8 af[4], bfr[4];
#pragma unroll
            for (int t = 0; t < 4; t++)
                af[t] = *(const bf16x8*)&As[(wm + t * 16 + ln) * 64 + co];
#pragma unroll
            for (int t = 0; t < 4; t++)
                bfr[t] = *(const bf16x8*)&Bs[(wn + t * 16 + ln) * 64 + co];
            if (swp) {
#pragma unroll
                for (int tm = 0; tm < 4; tm++)
#pragma unroll
                    for (int tn = 0; tn < 4; tn++)
                        acc[tm][tn] = __builtin_amdgcn_mfma_f32_16x16x32_bf16(
                            bfr[tn], af[tm], acc[tm][tn], 0, 0, 0);
            } else {
#pragma unroll
                for (int tm = 0; tm < 4; tm++)
#pragma unroll
                    for (int tn = 0; tn < 4; tn++)
                        acc[tm][tn] = __builtin_amdgcn_mfma_f32_16x16x32_bf16(
                            af[tm], bfr[tn], acc[tm][tn], 0, 0, 0);
            }
        }
    }

    if (swp) {
        // acc[tm][tn] = D^T block: lane ln -> s-row, regs -> 4 consecutive d
#pragma unroll
        for (int tm = 0; tm < 4; tm++)
#pragma unroll
            for (int tn = 0; tn < 4; tn++) {
                int mg = m0 + wm + tm * 16 + ln;            // s row (global among 4096)
                int nb = n0 + wn + tn * 16 + quad * 4;      // d col base
                int b = mg >> 11, s = mg & 2047, h = nb >> 6, dd = nb & 63;
                ushort4 o;
                o.x = f2bf(acc[tm][tn][0] * scl);
                o.y = f2bf(acc[tm][tn][1] * scl);
                o.z = f2bf(acc[tm][tn][2] * scl);
                o.w = f2bf(acc[tm][tn][3] * scl);
                size_t zoff = (size_t)z * (4096 * 1024);
                *(ushort4*)(outq + zoff + (((size_t)(b * 16 + h) * 2048 + s) << 6) + dd) = o;
            }
    } else {
        // V: normal D block: lane ln -> d, regs -> 4 consecutive s = one Vp permute group
#pragma unroll
        for (int tm = 0; tm < 4; tm++)
#pragma unroll
            for (int tn = 0; tn < 4; tn++) {
                int mg = m0 + wm + tm * 16 + quad * 4;      // s base (r spans 4)
                int ng = n0 + wn + tn * 16 + ln;            // d
                int b = mg >> 11, h = ng >> 6, dd = ng & 63;
                int sblk = (mg & 2047) & ~63;
                int cb = tm >> 1, t16 = tm & 1;
                int pp = cb * 32 + quad * 8 + t16 * 4;
                ushort4 o;
                o.x = f2bf(acc[tm][tn][0]);
                o.y = f2bf(acc[tm][tn][1]);
                o.z = f2bf(acc[tm][tn][2]);
                o.w = f2bf(acc[tm][tn][3]);
                *(ushort4*)(Vp + ((size_t)(b * 16 + h) * 64 + dd) * 2048 + sblk + pp) = o;
            }
    }
}

// ---------------- out-proj GEMM: out[4096][1024] = AO @ WoT^T, 128x128, XCD-swizzled ----
// Flat grid 256; all 8 n-blocks of an A m-tile on one XCD. Swapped mfma -> float4 stores.
// BK=64 single-buffer loop (1 block/CU -> every barrier drain fully exposed; halving
// drain count matters most here).
__global__ __launch_bounds__(256) void gemm_o(const unsigned short* __restrict__ A,
                                              const unsigned short* __restrict__ BT,
                                              float* __restrict__ outf) {
    __shared__ unsigned short As[128 * 64];
    __shared__ unsigned short Bs[128 * 64];
    const int tid = threadIdx.x;
    const int w = tid >> 6, lane = tid & 63, quad = lane >> 4, ln = lane & 15;

    const int blk = blockIdx.x;
    const int n0 = ((blk >> 3) & 7) * 128;
    const int m0 = (((blk >> 6) << 3) | (blk & 7)) * 128;   // 0..31 tiles

    const int lr8 = lane >> 3;
    const int lc8 = ((lane & 7) ^ lr8) * 8;
    const int fsw = (quad ^ (ln & 7)) * 8;

    const f32x4 z4 = {0.f, 0.f, 0.f, 0.f};
    f32x4 acc[4][4];
#pragma unroll
    for (int i = 0; i < 4; i++)
#pragma unroll
        for (int j = 0; j < 4; j++) acc[i][j] = z4;

    const int wm = (w & 1) * 64, wn = (w >> 1) * 64;
    const int Rb = w * 32;

    for (int k0 = 0; k0 < 1024; k0 += 64) {
        __syncthreads();
#pragma unroll
        for (int s = 0; s < 4; s++) {
            gld16(As + (Rb + s * 8) * 64, A  + (size_t)(m0 + Rb + s * 8 + lr8) * 1024 + k0 + lc8);
            gld16(Bs + (Rb + s * 8) * 64, BT + (size_t)(n0 + Rb + s * 8 + lr8) * 1024 + k0 + lc8);
        }
        __syncthreads();
#pragma unroll
        for (int ks = 0; ks < 2; ks++) {
            const int co = fsw ^ (ks * 32);
            bf16x8 af[4], bfr[4];
#pragma unroll
            for (int t = 0; t < 4; t++)
                af[t] = *(const bf16x8*)&As[(wm + t * 16 + ln) * 64 + co];
#pragma unroll
            for (int t = 0; t < 4; t++)
                bfr[t] = *(const bf16x8*)&Bs[(wn + t * 16 + ln) * 64 + co];
#pragma unroll
            for (int tm = 0; tm < 4; tm++)
#pragma unroll
                for (int tn = 0; tn < 4; tn++)
                    acc[tm][tn] = __builtin_amdgcn_mfma_f32_16x16x32_bf16(
                        bfr[tn], af[tm], acc[tm][tn], 0, 0, 0);
        }
    }

    // D^T blocks: lane ln -> output row, reg quad -> 4 consecutive cols -> float4 stores
#pragma unroll
    for (int tm = 0; tm < 4; tm++)
#pragma unroll
        for (int tn = 0; tn < 4; tn++) {
            int mg = m0 + wm + tm * 16 + ln;
            int nb = n0 + wn + tn * 16 + quad * 4;
            *(f32x4*)(outf + (size_t)mg * 1024 + nb) = acc[tm][tn];
        }
}

// ---------------- flash attention (128 q-rows/block, 8 waves, CU-balanced pairs) --------
// 8 waves x 16 q-rows, 64-col k-tiles, grid 512. Complementary-pair decode:
//   blk < 256:  bh = blk>>3, qi = blk&7        (light half, qi 0..7)
//   blk >= 256: bh = (blk-256)>>3, qi = 15-(blk&7)  (heavy half, qi 8..15)
// Under the observed dispatch map (CU = (blk%8)*32 + (blk/8)%32), CU c hosts blk c and
// c+256 whose qi sum to 15 -> EVERY CU gets exactly 34 k-tiles. XCDs balanced too.
// K/V staging double-buffered, ONE barrier per tile:
//   barrier (publishes cur) -> issue gld16 for k+1 into cur^1 -> compute(cur)
// Each wave stages 8 K-rows + 8 Vp-rows (2 gld16). XOR chunk swizzle (conflict-free).
// S^T = K Q^T keeps P in the PV B-fragment registers (permutation baked into Vp).
// Fixed-shift softmax, raw v_exp. PV skipped when whole tile is masked (wave-uniform).
__global__ __launch_bounds__(512, 4) void flash(const unsigned short* __restrict__ Qb,
                                                const unsigned short* __restrict__ Kb,
                                                const unsigned short* __restrict__ Vpb,
                                                unsigned short* __restrict__ AO) {
    __shared__ __align__(16) unsigned short Ks[2][64 * 64];
    __shared__ __align__(16) unsigned short Vs[2][64 * 64];
    const int tid = threadIdx.x, w = tid >> 6, lane = tid & 63;
    const int qd = lane >> 4, ln = lane & 15;
    const int lr = lane >> 3;                  // row-within-8 for staging
    const int lchunk = (lane & 7) ^ lr;        // swizzled source 16B-chunk
    const int psw = (qd ^ (ln & 7)) * 8;       // swizzled read chunk offset (elems)

    const int blk = blockIdx.x;
    const int b2 = blk & 255;
    const int bh = b2 >> 3;                          // 0..31
    const int q7 = b2 & 7;
    const int qi = (blk < 256) ? q7 : (15 - q7);     // complementary pair across halves
    const int qt0 = qi * 128;

    const unsigned short* Kg = Kb  + (size_t)bh * 2048 * 64;
    const unsigned short* Vg = Vpb + (size_t)bh * 64 * 2048;

    // Q fragment (B-operand of S^T MFMA): lane ln holds Q[qt0+w*16+ln][qd*8+jj]
    bf16x8 aq[2];
    {
        const unsigned short* Qrow = Qb + ((size_t)bh * 2048 + qt0 + w * 16 + ln) * 64 + qd * 8;
        aq[0] = *(const bf16x8*)(Qrow);
        aq[1] = *(const bf16x8*)(Qrow + 32);
    }

    const f32x4 z4 = {0.f, 0.f, 0.f, 0.f};
    f32x4 Oc[4];
#pragma unroll
    for (int td = 0; td < 4; td++) Oc[td] = z4;
    float lsum = 0.f;

    const int qrow = qt0 + w * 16 + ln;   // lane's q row (S^T: q indexed by ln)
    const int qmin = qt0 + w * 16;
    const int qmax = qmin + 15;
    const int kend = qt0 + 128;

    // stage(buf, kk): wave w fills K rows [w*8,w*8+8) and Vp d-rows [w*8,w*8+8)
#define FLASH_STAGE(buf, kk)                                                          \
    {                                                                                 \
        const unsigned short* kg = Kg + (size_t)((kk) + w * 8 + lr) * 64 + lchunk * 8; \
        gld16(&Ks[buf][(w * 8) * 64], kg);                                            \
        const unsigned short* vg = Vg + (size_t)(w * 8 + lr) * 2048 + (kk) + lchunk * 8; \
        gld16(&Vs[buf][(w * 8) * 64], vg);                                            \
    }

    FLASH_STAGE(0, 0);
    int cur = 0;

    for (int k0 = 0; k0 < kend; k0 += 64) {
        __syncthreads();                    // publishes buf cur (drains staging vmcnt)
        if (k0 + 64 < kend) FLASH_STAGE(cur ^ 1, k0 + 64);

        if (k0 <= qmax) {                   // wave-uniform: tile contributes for this wave
            // S^T = K Q^T : output lane (qd,ln) reg r = S[q=ln][kk = t*16 + qd*4 + r]
            f32x4 sc[4];
#pragma unroll
            for (int t = 0; t < 4; t++) {
                sc[t] = z4;
                if (k0 + t * 16 <= qmax) {
                    int off = (t * 16 + ln) * 64 + psw;
                    bf16x8 bk0 = *(const bf16x8*)&Ks[cur][off];
                    bf16x8 bk1 = *(const bf16x8*)&Ks[cur][off ^ 32];
                    sc[t] = __builtin_amdgcn_mfma_f32_16x16x32_bf16(bk0, aq[0], sc[t], 0, 0, 0);
                    sc[t] = __builtin_amdgcn_mfma_f32_16x16x32_bf16(bk1, aq[1], sc[t], 0, 0, 0);
                }
            }

            // P = exp2(S) (fixed shift), causal mask only in crossing band; pack bf16x2
            unsigned int pk[4][2];
#pragma unroll
            for (int t = 0; t < 4; t++) {
                if (k0 + t * 16 > qmax) { pk[t][0] = 0u; pk[t][1] = 0u; continue; }
                float e[4];
#pragma unroll
                for (int r2 = 0; r2 < 4; r2++) e[r2] = __builtin_amdgcn_exp2f(sc[t][r2]);
                if (k0 + t * 16 + 15 > qmin) {
#pragma unroll
                    for (int r2 = 0; r2 < 4; r2++)
                        if (k0 + t * 16 + qd * 4 + r2 > qrow) e[r2] = 0.f;
                }
                lsum += (e[0] + e[1]) + (e[2] + e[3]);
                pk[t][0] = (unsigned int)f2bf(e[0]) | ((unsigned int)f2bf(e[1]) << 16);
                pk[t][1] = (unsigned int)f2bf(e[2]) | ((unsigned int)f2bf(e[3]) << 16);
            }

            // O^T += V^T P^T under permuted contraction: B-frag(c) = own regs pk[2c..2c+1]
            union { unsigned int u[4]; bf16x8 v; } apu0, apu1;
            apu0.u[0] = pk[0][0]; apu0.u[1] = pk[0][1]; apu0.u[2] = pk[1][0]; apu0.u[3] = pk[1][1];
            apu1.u[0] = pk[2][0]; apu1.u[1] = pk[2][1]; apu1.u[2] = pk[3][0]; apu1.u[3] = pk[3][1];
#pragma unroll
            for (int td = 0; td < 4; td++) {
                int voff = (td * 16 + ln) * 64 + psw;
                bf16x8 av0 = *(const bf16x8*)&Vs[cur][voff];
                bf16x8 av1 = *(const bf16x8*)&Vs[cur][voff ^ 32];
                Oc[td] = __builtin_amdgcn_mfma_f32_16x16x32_bf16(av0, apu0.v, Oc[td], 0, 0, 0);
                Oc[td] = __builtin_amdgcn_mfma_f32_16x16x32_bf16(av1, apu1.v, Oc[td], 0, 0, 0);
            }
        }
        cur ^= 1;
    }
#undef FLASH_STAGE

    // row-sum butterfly across quads (lanes ln, ln+16, ln+32, ln+48 hold partials)
    lsum += __shfl_xor(lsum, 16);
    lsum += __shfl_xor(lsum, 32);
    const float inv = 1.0f / lsum;

    // O^T output: lane (qd,ln) reg (td,r) = O[q=ln][d = td*16 + qd*4 + r]
    const int bz = bh >> 4, h = bh & 15;
    const int rowg = qt0 + w * 16 + ln;
    unsigned short* aorow = AO + ((size_t)(bz * 2048 + rowg) << 10) + h * 64 + qd * 4;
#pragma unroll
    for (int td = 0; td < 4; td++) {
        ushort4 o;
        o.x = f2bf(Oc[td][0] * inv);
        o.y = f2bf(Oc[td][1] * inv);
        o.z = f2bf(Oc[td][2] * inv);
        o.w = f2bf(Oc[td][3] * inv);
        *(ushort4*)(aorow + td * 16) = o;
    }
}

extern "C" void kernel_launch(void* const* d_in, const int* in_sizes, int n_in,
                              void* d_out, int out_size, void* d_ws, size_t ws_size,
                              hipStream_t stream) {
    const float* x  = (const float*)d_in[0];
    const float* Wq = (const float*)d_in[1];
    const float* Wk = (const float*)d_in[2];
    const float* Wv = (const float*)d_in[3];
    const float* Wo = (const float*)d_in[4];
    float* out = (float*)d_out;

    unsigned short* xb  = (unsigned short*)d_ws;           // 4096*1024
    unsigned short* WT  = xb  + (size_t)4096 * 1024;       // 4*1024*1024
    unsigned short* Qb  = WT  + (size_t)4 * 1024 * 1024;   // Q,K contiguous ([B][H][S][64])
    unsigned short* Kb  = Qb  + (size_t)4096 * 1024;
    unsigned short* Vb  = Kb  + (size_t)4096 * 1024;       // unused (kept for layout stability)
    unsigned short* Vpb = Vb  + (size_t)4096 * 1024;       // Vp [B][H][64][S] permuted
    unsigned short* AO  = Vpb + (size_t)4096 * 1024;

    castx<<<4096, 256, 0, stream>>>(x, xb);
    wtrans<<<dim3(16, 16, 4), 256, 0, stream>>>(Wq, Wk, Wv, Wo, WT);
    gemm_qkv<<<dim3(768), 256, 0, stream>>>(xb, WT, Qb, Vpb);
    flash<<<dim3(512), 512, 0, stream>>>(Qb, Kb, Vpb, AO);
    gemm_o<<<dim3(256), 256, 0, stream>>>(AO, WT + (size_t)3 * 1024 * 1024, out);
}

// Round 7
// 180.141 us; speedup vs baseline: 1.0693x; 1.0478x over previous
//
#include <hip/hip_runtime.h>

// StandardAttention: B=2,S=2048,D=1024,H=16,DQK=DV=64. fp32 in/out, bf16 MFMA inside.
// Workspace layout (56 MB):
//   xb  [4096][1024] bf16           8 MB   (dead after gemm_qkv -> reused: heavy half1 fp32 partials)
//   WT  [4][1024][1024] bf16 (W^T)  8 MB   (z=0 dead after gemm_qkv -> first 256KB = lsum partials)
//   Q,K [B][H][S][64] bf16          16 MB  (Q pre-scaled by 0.125*log2(e))
//   Vb  (unused slot)               8 MB   (reused: heavy half0 fp32 partials)
//   Vp  [B][H][64][S] bf16          8 MB
//   AO  [B][S][1024] bf16           8 MB
//
// R2: BK=64 single-buffer GEMM loops (kept). R1/R5/R6 lessons in git log.
// R6 post-mortem: duration invariant (~48us) across 4 schedules AND a 3.3x FETCH swing
//   -> not balance-, not BW-bound. The qi=15 block's 32 k-tiles are a SERIAL chain
//   (~1.5us/tile); schedules can't redistribute tiles within a block.
// R7: SPLIT-K on heavy q-tiles. Fixed-shift softmax => partial (O,lsum) over disjoint
//   k-ranges are addable. qi 8..15 split at k=(qi+1)*64 into 2 blocks: half0 fully
//   below diagonal (no masking), half1 has the crossing band. Heavy blocks write fp32
//   partials to dead ws; merge kernel normalizes into AO. Grid 768 = 3 blocks/CU; slot
//   decode gives every CU light(2s+2)+2x(16-s) = 34 tiles, max serial chain 16 (was 32).

typedef float  f32x4  __attribute__((ext_vector_type(4)));
typedef __bf16 bf16x8 __attribute__((ext_vector_type(8)));

__device__ __forceinline__ unsigned short f2bf(float f) {
    __bf16 h = (__bf16)f;
    return __builtin_bit_cast(unsigned short, h);
}

// async global->LDS, 16B per lane; lds base wave-uniform (HW: base + lane*16)
__device__ __forceinline__ void gld16(unsigned short* lds, const unsigned short* g) {
    __builtin_amdgcn_global_load_lds(
        (const __attribute__((address_space(1))) void*)g,
        (__attribute__((address_space(3))) void*)lds, 16, 0, 0);
}

// ---------------- cast x -> bf16 ----------------
__global__ __launch_bounds__(256) void castx(const float* __restrict__ x,
                                             unsigned short* __restrict__ xb) {
    size_t i = ((size_t)blockIdx.x * 256 + threadIdx.x) * 4;
    float4 v = *(const float4*)(x + i);
    ushort4 o;
    o.x = f2bf(v.x); o.y = f2bf(v.y); o.z = f2bf(v.z); o.w = f2bf(v.w);
    *(ushort4*)(xb + i) = o;
}

// ---------------- transpose+cast weights: W[1024][1024] f32 -> WT[z][1024][1024] bf16 ----
__global__ __launch_bounds__(256) void wtrans(const float* __restrict__ W0,
                                              const float* __restrict__ W1,
                                              const float* __restrict__ W2,
                                              const float* __restrict__ W3,
                                              unsigned short* __restrict__ WT) {
    __shared__ float T[64][65];
    const int z = blockIdx.z;
    const float* W = (z == 0) ? W0 : (z == 1) ? W1 : (z == 2) ? W2 : W3;
    const int k0 = blockIdx.y * 64, n0 = blockIdx.x * 64;
    const int tid = threadIdx.x;
#pragma unroll
    for (int i = 0; i < 4; i++) {
        int c = tid + i * 256;
        int r = c >> 4, col = (c & 15) * 4;
        float4 v = *(const float4*)(W + (size_t)(k0 + r) * 1024 + n0 + col);
        T[r][col] = v.x; T[r][col + 1] = v.y; T[r][col + 2] = v.z; T[r][col + 3] = v.w;
    }
    __syncthreads();
    unsigned short* out = WT + (size_t)z * 1024 * 1024;
#pragma unroll
    for (int i = 0; i < 2; i++) {
        int c = tid + i * 256;
        int nr = c >> 3, koff = (c & 7) * 8;
        union { unsigned short us[8]; uint4 v; } pk;
#pragma unroll
        for (int j = 0; j < 8; j++) pk.us[j] = f2bf(T[koff + j][nr]);
        *(uint4*)(out + (size_t)(n0 + nr) * 1024 + k0 + koff) = pk.v;
    }
}

// ---------------- QKV GEMM: [4096][1024] x WT^T per z; BK=64, XCD-swizzled grid --------
__global__ __launch_bounds__(256) void gemm_qkv(const unsigned short* __restrict__ A,
                                                const unsigned short* __restrict__ WTall,
                                                unsigned short* __restrict__ outq,
                                                unsigned short* __restrict__ Vp) {
    __shared__ unsigned short As[128 * 64];
    __shared__ unsigned short Bs[128 * 64];
    const int tid = threadIdx.x;
    const int w = tid >> 6, lane = tid & 63, quad = lane >> 4, ln = lane & 15;

    const int blk = blockIdx.x;
    const int n0 = ((blk >> 3) & 7) * 128;
    const int g  = ((blk >> 6) << 3) | (blk & 7);   // 0..95 = z*32+m
    const int z  = g >> 5;
    const int m0 = (g & 31) * 128;

    const unsigned short* BT = WTall + (size_t)z * (1024 * 1024);
    const float scl = (z == 0) ? 0.180336878f : 1.0f;
    const bool swp = (z < 2);

    const int lr8 = lane >> 3;                      // row within 8-row staging group
    const int lc8 = ((lane & 7) ^ lr8) * 8;         // XOR-swizzled source chunk (elems)
    const int fsw = (quad ^ (ln & 7)) * 8;          // swizzled frag-read chunk (elems)

    const f32x4 z4 = {0.f, 0.f, 0.f, 0.f};
    f32x4 acc[4][4];
#pragma unroll
    for (int i = 0; i < 4; i++)
#pragma unroll
        for (int j = 0; j < 4; j++) acc[i][j] = z4;

    const int wm = (w & 1) * 64, wn = (w >> 1) * 64;
    const int Rb = w * 32;                          // staging row base for this wave

    for (int k0 = 0; k0 < 1024; k0 += 64) {
        __syncthreads();
#pragma unroll
        for (int s = 0; s < 4; s++) {
            gld16(As + (Rb + s * 8) * 64, A  + (size_t)(m0 + Rb + s * 8 + lr8) * 1024 + k0 + lc8);
            gld16(Bs + (Rb + s * 8) * 64, BT + (size_t)(n0 + Rb + s * 8 + lr8) * 1024 + k0 + lc8);
        }
        __syncthreads();
#pragma unroll
        for (int ks = 0; ks < 2; ks++) {
            const int co = fsw ^ (ks * 32);         // elem offset: chunk quad (+4 for ks=1)
            bf16x8 af[4], bfr[4];
#pragma unroll
            for (int t = 0; t < 4; t++)
                af[t] = *(const bf16x8*)&As[(wm + t * 16 + ln) * 64 + co];
#pragma unroll
            for (int t = 0; t < 4; t++)
                bfr[t] = *(const bf16x8*)&Bs[(wn + t * 16 + ln) * 64 + co];
            if (swp) {
#pragma unroll
                for (int tm = 0; tm < 4; tm++)
#pragma unroll
                    for (int tn = 0; tn < 4; tn++)
                        acc[tm][tn] = __builtin_amdgcn_mfma_f32_16x16x32_bf16(
                            bfr[tn], af[tm], acc[tm][tn], 0, 0, 0);
            } else {
#pragma unroll
                for (int tm = 0; tm < 4; tm++)
#pragma unroll
                    for (int tn = 0; tn < 4; tn++)
                        acc[tm][tn] = __builtin_amdgcn_mfma_f32_16x16x32_bf16(
                            af[tm], bfr[tn], acc[tm][tn], 0, 0, 0);
            }
        }
    }

    if (swp) {
        // acc[tm][tn] = D^T block: lane ln -> s-row, regs -> 4 consecutive d
#pragma unroll
        for (int tm = 0; tm < 4; tm++)
#pragma unroll
            for (int tn = 0; tn < 4; tn++) {
                int mg = m0 + wm + tm * 16 + ln;            // s row (global among 4096)
                int nb = n0 + wn + tn * 16 + quad * 4;      // d col base
                int b = mg >> 11, s = mg & 2047, h = nb >> 6, dd = nb & 63;
                ushort4 o;
                o.x = f2bf(acc[tm][tn][0] * scl);
                o.y = f2bf(acc[tm][tn][1] * scl);
                o.z = f2bf(acc[tm][tn][2] * scl);
                o.w = f2bf(acc[tm][tn][3] * scl);
                size_t zoff = (size_t)z * (4096 * 1024);
                *(ushort4*)(outq + zoff + (((size_t)(b * 16 + h) * 2048 + s) << 6) + dd) = o;
            }
    } else {
        // V: normal D block: lane ln -> d, regs -> 4 consecutive s = one Vp permute group
#pragma unroll
        for (int tm = 0; tm < 4; tm++)
#pragma unroll
            for (int tn = 0; tn < 4; tn++) {
                int mg = m0 + wm + tm * 16 + quad * 4;      // s base (r spans 4)
                int ng = n0 + wn + tn * 16 + ln;            // d
                int b = mg >> 11, h = ng >> 6, dd = ng & 63;
                int sblk = (mg & 2047) & ~63;
                int cb = tm >> 1, t16 = tm & 1;
                int pp = cb * 32 + quad * 8 + t16 * 4;
                ushort4 o;
                o.x = f2bf(acc[tm][tn][0]);
                o.y = f2bf(acc[tm][tn][1]);
                o.z = f2bf(acc[tm][tn][2]);
                o.w = f2bf(acc[tm][tn][3]);
                *(ushort4*)(Vp + ((size_t)(b * 16 + h) * 64 + dd) * 2048 + sblk + pp) = o;
            }
    }
}

// ---------------- out-proj GEMM: out[4096][1024] = AO @ WoT^T, 128x128, XCD-swizzled ----
__global__ __launch_bounds__(256) void gemm_o(const unsigned short* __restrict__ A,
                                              const unsigned short* __restrict__ BT,
                                              float* __restrict__ outf) {
    __shared__ unsigned short As[128 * 64];
    __shared__ unsigned short Bs[128 * 64];
    const int tid = threadIdx.x;
    const int w = tid >> 6, lane = tid & 63, quad = lane >> 4, ln = lane & 15;

    const int blk = blockIdx.x;
    const int n0 = ((blk >> 3) & 7) * 128;
    const int m0 = (((blk >> 6) << 3) | (blk & 7)) * 128;   // 0..31 tiles

    const int lr8 = lane >> 3;
    const int lc8 = ((lane & 7) ^ lr8) * 8;
    const int fsw = (quad ^ (ln & 7)) * 8;

    const f32x4 z4 = {0.f, 0.f, 0.f, 0.f};
    f32x4 acc[4][4];
#pragma unroll
    for (int i = 0; i < 4; i++)
#pragma unroll
        for (int j = 0; j < 4; j++) acc[i][j] = z4;

    const int wm = (w & 1) * 64, wn = (w >> 1) * 64;
    const int Rb = w * 32;

    for (int k0 = 0; k0 < 1024; k0 += 64) {
        __syncthreads();
#pragma unroll
        for (int s = 0; s < 4; s++) {
            gld16(As + (Rb + s * 8) * 64, A  + (size_t)(m0 + Rb + s * 8 + lr8) * 1024 + k0 + lc8);
            gld16(Bs + (Rb + s * 8) * 64, BT + (size_t)(n0 + Rb + s * 8 + lr8) * 1024 + k0 + lc8);
        }
        __syncthreads();
#pragma unroll
        for (int ks = 0; ks < 2; ks++) {
            const int co = fsw ^ (ks * 32);
            bf16x8 af[4], bfr[4];
#pragma unroll
            for (int t = 0; t < 4; t++)
                af[t] = *(const bf16x8*)&As[(wm + t * 16 + ln) * 64 + co];
#pragma unroll
            for (int t = 0; t < 4; t++)
                bfr[t] = *(const bf16x8*)&Bs[(wn + t * 16 + ln) * 64 + co];
#pragma unroll
            for (int tm = 0; tm < 4; tm++)
#pragma unroll
                for (int tn = 0; tn < 4; tn++)
                    acc[tm][tn] = __builtin_amdgcn_mfma_f32_16x16x32_bf16(
                        bfr[tn], af[tm], acc[tm][tn], 0, 0, 0);
        }
    }

    // D^T blocks: lane ln -> output row, reg quad -> 4 consecutive cols -> float4 stores
#pragma unroll
    for (int tm = 0; tm < 4; tm++)
#pragma unroll
        for (int tn = 0; tn < 4; tn++) {
            int mg = m0 + wm + tm * 16 + ln;
            int nb = n0 + wn + tn * 16 + quad * 4;
            *(f32x4*)(outf + (size_t)mg * 1024 + nb) = acc[tm][tn];
        }
}

// ---------------- flash attention (split-K heavy tiles, 8 waves, grid 768) --------------
// Slot decode: bh = blk&31, s = blk>>5 (0..23).
//   s<8:    light q-tile qi=s, full k range [0,(qi+1)*128), normalize, write AO.
//   s>=8:   heavy q-tile qi=15-((s-8)&7), half=(s-8)>>3; k in [0,mid) or [mid,(qi+1)*128),
//           mid=(qi+1)*64; write fp32 partial O + lsum to workspace (merged later).
// CU triple (s, s+8, s+16) = light(2s+2) + 2x(16-s) tiles = 34 for every CU; max serial
// chain 16 tiles. XCD = blk&7 = bh&7 -> 4 heads/XCD (2MB K/V, L2-resident).
// Dbuf staging, ONE barrier per tile; XOR chunk swizzle; S^T = K Q^T; fixed-shift exp2
// (makes disjoint-k partials addable: O_tot = O0+O1, l_tot = l0+l1).
__global__ __launch_bounds__(512, 4) void flash(const unsigned short* __restrict__ Qb,
                                                const unsigned short* __restrict__ Kb,
                                                const unsigned short* __restrict__ Vpb,
                                                unsigned short* __restrict__ AO,
                                                float* __restrict__ Ph0,
                                                float* __restrict__ Ph1,
                                                float* __restrict__ Lb) {
    __shared__ __align__(16) unsigned short Ks[2][64 * 64];
    __shared__ __align__(16) unsigned short Vs[2][64 * 64];
    const int tid = threadIdx.x, w = tid >> 6, lane = tid & 63;
    const int qd = lane >> 4, ln = lane & 15;
    const int lr = lane >> 3;                  // row-within-8 for staging
    const int lchunk = (lane & 7) ^ lr;        // swizzled source 16B-chunk
    const int psw = (qd ^ (ln & 7)) * 8;       // swizzled read chunk offset (elems)

    const int blk = blockIdx.x;
    const int bh = blk & 31;
    const int s  = blk >> 5;                   // 0..23
    int qi, kstart, kend, half;
    bool heavy;
    if (s < 8) {
        qi = s; kstart = 0; kend = (qi + 1) * 128; half = 0; heavy = false;
    } else {
        int t = s - 8; half = t >> 3; qi = 15 - (t & 7); heavy = true;
        int mid = (qi + 1) * 64;
        kstart = half ? mid : 0;
        kend   = half ? (qi + 1) * 128 : mid;
    }
    const int qt0 = qi * 128;

    const unsigned short* Kg = Kb  + (size_t)bh * 2048 * 64;
    const unsigned short* Vg = Vpb + (size_t)bh * 64 * 2048;

    // Q fragment (B-operand of S^T MFMA): lane ln holds Q[qt0+w*16+ln][qd*8+j]
    bf16x8 aq[2];
    {
        const unsigned short* Qrow = Qb + ((size_t)bh * 2048 + qt0 + w * 16 + ln) * 64 + qd * 8;
        aq[0] = *(const bf16x8*)(Qrow);
        aq[1] = *(const bf16x8*)(Qrow + 32);
    }

    const f32x4 z4 = {0.f, 0.f, 0.f, 0.f};
    f32x4 Oc[4];
#pragma unroll
    for (int td = 0; td < 4; td++) Oc[td] = z4;
    float lsum = 0.f;

    const int qrow = qt0 + w * 16 + ln;   // lane's q row (S^T: q indexed by ln)
    const int qmin = qt0 + w * 16;
    const int qmax = qmin + 15;

    // stage(buf, kk): wave w fills K rows [w*8,w*8+8) and Vp d-rows [w*8,w*8+8)
#define FLASH_STAGE(buf, kk)                                                          \
    {                                                                                 \
        const unsigned short* kg = Kg + (size_t)((kk) + w * 8 + lr) * 64 + lchunk * 8; \
        gld16(&Ks[buf][(w * 8) * 64], kg);                                            \
        const unsigned short* vg = Vg + (size_t)(w * 8 + lr) * 2048 + (kk) + lchunk * 8; \
        gld16(&Vs[buf][(w * 8) * 64], vg);                                            \
    }

    FLASH_STAGE(0, kstart);
    int cur = 0;

    for (int k0 = kstart; k0 < kend; k0 += 64) {
        __syncthreads();                    // publishes buf cur (drains staging vmcnt)
        if (k0 + 64 < kend) FLASH_STAGE(cur ^ 1, k0 + 64);

        if (k0 <= qmax) {                   // wave-uniform: tile contributes for this wave
            // S^T = K Q^T : output lane (qd,ln) reg r = S[q=ln][kk = t*16 + qd*4 + r]
            f32x4 sc[4];
#pragma unroll
            for (int t = 0; t < 4; t++) {
                sc[t] = z4;
                if (k0 + t * 16 <= qmax) {
                    int off = (t * 16 + ln) * 64 + psw;
                    bf16x8 bk0 = *(const bf16x8*)&Ks[cur][off];
                    bf16x8 bk1 = *(const bf16x8*)&Ks[cur][off ^ 32];
                    sc[t] = __builtin_amdgcn_mfma_f32_16x16x32_bf16(bk0, aq[0], sc[t], 0, 0, 0);
                    sc[t] = __builtin_amdgcn_mfma_f32_16x16x32_bf16(bk1, aq[1], sc[t], 0, 0, 0);
                }
            }

            // P = exp2(S) (fixed shift), causal mask only in crossing band; pack bf16x2
            unsigned int pk[4][2];
#pragma unroll
            for (int t = 0; t < 4; t++) {
                if (k0 + t * 16 > qmax) { pk[t][0] = 0u; pk[t][1] = 0u; continue; }
                float e[4];
#pragma unroll
                for (int r2 = 0; r2 < 4; r2++) e[r2] = __builtin_amdgcn_exp2f(sc[t][r2]);
                if (k0 + t * 16 + 15 > qmin) {
#pragma unroll
                    for (int r2 = 0; r2 < 4; r2++)
                        if (k0 + t * 16 + qd * 4 + r2 > qrow) e[r2] = 0.f;
                }
                lsum += (e[0] + e[1]) + (e[2] + e[3]);
                pk[t][0] = (unsigned int)f2bf(e[0]) | ((unsigned int)f2bf(e[1]) << 16);
                pk[t][1] = (unsigned int)f2bf(e[2]) | ((unsigned int)f2bf(e[3]) << 16);
            }

            // O^T += V^T P^T under permuted contraction: B-frag(c) = own regs pk[2c..2c+1]
            union { unsigned int u[4]; bf16x8 v; } apu0, apu1;
            apu0.u[0] = pk[0][0]; apu0.u[1] = pk[0][1]; apu0.u[2] = pk[1][0]; apu0.u[3] = pk[1][1];
            apu1.u[0] = pk[2][0]; apu1.u[1] = pk[2][1]; apu1.u[2] = pk[3][0]; apu1.u[3] = pk[3][1];
#pragma unroll
            for (int td = 0; td < 4; td++) {
                int voff = (td * 16 + ln) * 64 + psw;
                bf16x8 av0 = *(const bf16x8*)&Vs[cur][voff];
                bf16x8 av1 = *(const bf16x8*)&Vs[cur][voff ^ 32];
                Oc[td] = __builtin_amdgcn_mfma_f32_16x16x32_bf16(av0, apu0.v, Oc[td], 0, 0, 0);
                Oc[td] = __builtin_amdgcn_mfma_f32_16x16x32_bf16(av1, apu1.v, Oc[td], 0, 0, 0);
            }
        }
        cur ^= 1;
    }
#undef FLASH_STAGE

    // row-sum butterfly across quads (lanes ln, ln+16, ln+32, ln+48 hold partials)
    lsum += __shfl_xor(lsum, 16);
    lsum += __shfl_xor(lsum, 32);

    if (!heavy) {
        const float inv = 1.0f / lsum;
        // O^T output: lane (qd,ln) reg (td,r) = O[q=ln][d = td*16 + qd*4 + r]
        const int bz = bh >> 4, h = bh & 15;
        const int rowg = qt0 + w * 16 + ln;
        unsigned short* aorow = AO + ((size_t)(bz * 2048 + rowg) << 10) + h * 64 + qd * 4;
#pragma unroll
        for (int td = 0; td < 4; td++) {
            ushort4 o;
            o.x = f2bf(Oc[td][0] * inv);
            o.y = f2bf(Oc[td][1] * inv);
            o.z = f2bf(Oc[td][2] * inv);
            o.w = f2bf(Oc[td][3] * inv);
            *(ushort4*)(aorow + td * 16) = o;
        }
    } else {
        // fp32 partial: P[(bh*8+qi-8)*128 + q][64]; lsum -> Lb[half*32768 + prow]
        float* P = half ? Ph1 : Ph0;
        const int prow = ((bh * 8 + (qi - 8)) * 128) + w * 16 + ln;
        float* Pr = P + (size_t)prow * 64 + qd * 4;
#pragma unroll
        for (int td = 0; td < 4; td++)
            *(f32x4*)(Pr + td * 16) = Oc[td];
        if (qd == 0) Lb[half * 32768 + prow] = lsum;
    }
}

// ---------------- merge heavy split-K partials -> AO ------------------------------------
// 32768 rows x 64 d; thread handles 8 d. O = (P0+P1)/(l0+l1), bf16, into AO heavy rows.
__global__ __launch_bounds__(256) void merge(const float* __restrict__ P0,
                                             const float* __restrict__ P1,
                                             const float* __restrict__ Lb,
                                             unsigned short* __restrict__ AO) {
    const int idx = blockIdx.x * 256 + threadIdx.x;   // 0..262143
    const int d0 = (idx & 7) * 8;
    const int row = idx >> 3;                          // (bh*8+qi8)*128 + q
    const float inv = 1.0f / (Lb[row] + Lb[32768 + row]);
    const float* a = P0 + (size_t)row * 64 + d0;
    const float* b = P1 + (size_t)row * 64 + d0;
    f32x4 x0 = *(const f32x4*)a, x1 = *(const f32x4*)(a + 4);
    f32x4 y0 = *(const f32x4*)b, y1 = *(const f32x4*)(b + 4);
    union { unsigned short us[8]; uint4 v; } pk;
#pragma unroll
    for (int j = 0; j < 4; j++) {
        pk.us[j]     = f2bf((x0[j] + y0[j]) * inv);
        pk.us[j + 4] = f2bf((x1[j] + y1[j]) * inv);
    }
    const int bh = row >> 10, qi8 = (row >> 7) & 7, q = row & 127;
    const int bz = bh >> 4, h = bh & 15;
    const int rowg = (qi8 + 8) * 128 + q;
    *(uint4*)(AO + ((size_t)(bz * 2048 + rowg) << 10) + h * 64 + d0) = pk.v;
}

extern "C" void kernel_launch(void* const* d_in, const int* in_sizes, int n_in,
                              void* d_out, int out_size, void* d_ws, size_t ws_size,
                              hipStream_t stream) {
    const float* x  = (const float*)d_in[0];
    const float* Wq = (const float*)d_in[1];
    const float* Wk = (const float*)d_in[2];
    const float* Wv = (const float*)d_in[3];
    const float* Wo = (const float*)d_in[4];
    float* out = (float*)d_out;

    unsigned short* xb  = (unsigned short*)d_ws;           // 4096*1024
    unsigned short* WT  = xb  + (size_t)4096 * 1024;       // 4*1024*1024
    unsigned short* Qb  = WT  + (size_t)4 * 1024 * 1024;   // Q,K contiguous ([B][H][S][64])
    unsigned short* Kb  = Qb  + (size_t)4096 * 1024;
    unsigned short* Vb  = Kb  + (size_t)4096 * 1024;       // dead slot -> half0 partials
    unsigned short* Vpb = Vb  + (size_t)4096 * 1024;       // Vp [B][H][64][S] permuted
    unsigned short* AO  = Vpb + (size_t)4096 * 1024;

    float* Ph0 = (float*)Vb;   // 8 MB: heavy half0 fp32 partial O (exactly 2M floats)
    float* Ph1 = (float*)xb;   // 8 MB: heavy half1 (xb dead after gemm_qkv)
    float* Lb  = (float*)WT;   // 256 KB: lsum partials (Wq^T region dead after gemm_qkv)

    castx<<<4096, 256, 0, stream>>>(x, xb);
    wtrans<<<dim3(16, 16, 4), 256, 0, stream>>>(Wq, Wk, Wv, Wo, WT);
    gemm_qkv<<<dim3(768), 256, 0, stream>>>(xb, WT, Qb, Vpb);
    flash<<<dim3(768), 512, 0, stream>>>(Qb, Kb, Vpb, AO, Ph0, Ph1, Lb);
    merge<<<dim3(1024), 256, 0, stream>>>(Ph0, Ph1, Lb, AO);
    gemm_o<<<dim3(256), 256, 0, stream>>>(AO, WT + (size_t)3 * 1024 * 1024, out);
}

// Round 8
// 170.082 us; speedup vs baseline: 1.1326x; 1.0591x over previous
//
#include <hip/hip_runtime.h>

// StandardAttention: B=2,S=2048,D=1024,H=16,DQK=DV=64. fp32 in/out, bf16 MFMA inside.
// Workspace layout (56 MB):
//   xb  [4096][1024] bf16           8 MB   (dead after gemm_qkv -> reused: heavy half1 fp32 partials)
//   WT  [4][1024][1024] bf16 (W^T)  8 MB   (z=0 dead after gemm_qkv -> first 256KB = lsum partials)
//   Q,K [B][H][S][64] bf16          16 MB  (Q pre-scaled by 0.125*log2(e))
//   Vb  (unused slot)               8 MB   (reused: heavy half0 fp32 partials)
//   Vp  [B][H][64][S] bf16          8 MB
//   AO  [B][S][1024] bf16           8 MB
//
// R2: BK=64. R7: split-K heavy flash tiles + merge (flash off top-5).
// R7 post-mortem: gemm_qkv now the top dispatch (44us, MfmaUtil 21%, 68% idle) --
//   2-barrier K-step exposes full staging latency every step.
// R8: single-barrier double-buffered K-loop via STATIC x2 unroll (As0/As1/Bs0/Bs1 --
//   no runtime cur, which is what sank R1). Per step: barrier publishes buf, NEXT
//   step's stage issues immediately, compute overlaps its latency. 64KB LDS -> 2
//   blocks/CU. Same transform in gemm_o.

typedef float  f32x4  __attribute__((ext_vector_type(4)));
typedef __bf16 bf16x8 __attribute__((ext_vector_type(8)));

__device__ __forceinline__ unsigned short f2bf(float f) {
    __bf16 h = (__bf16)f;
    return __builtin_bit_cast(unsigned short, h);
}

// async global->LDS, 16B per lane; lds base wave-uniform (HW: base + lane*16)
__device__ __forceinline__ void gld16(unsigned short* lds, const unsigned short* g) {
    __builtin_amdgcn_global_load_lds(
        (const __attribute__((address_space(1))) void*)g,
        (__attribute__((address_space(3))) void*)lds, 16, 0, 0);
}

// ---------------- cast x -> bf16 ----------------
__global__ __launch_bounds__(256) void castx(const float* __restrict__ x,
                                             unsigned short* __restrict__ xb) {
    size_t i = ((size_t)blockIdx.x * 256 + threadIdx.x) * 4;
    float4 v = *(const float4*)(x + i);
    ushort4 o;
    o.x = f2bf(v.x); o.y = f2bf(v.y); o.z = f2bf(v.z); o.w = f2bf(v.w);
    *(ushort4*)(xb + i) = o;
}

// ---------------- transpose+cast weights: W[1024][1024] f32 -> WT[z][1024][1024] bf16 ----
__global__ __launch_bounds__(256) void wtrans(const float* __restrict__ W0,
                                              const float* __restrict__ W1,
                                              const float* __restrict__ W2,
                                              const float* __restrict__ W3,
                                              unsigned short* __restrict__ WT) {
    __shared__ float T[64][65];
    const int z = blockIdx.z;
    const float* W = (z == 0) ? W0 : (z == 1) ? W1 : (z == 2) ? W2 : W3;
    const int k0 = blockIdx.y * 64, n0 = blockIdx.x * 64;
    const int tid = threadIdx.x;
#pragma unroll
    for (int i = 0; i < 4; i++) {
        int c = tid + i * 256;
        int r = c >> 4, col = (c & 15) * 4;
        float4 v = *(const float4*)(W + (size_t)(k0 + r) * 1024 + n0 + col);
        T[r][col] = v.x; T[r][col + 1] = v.y; T[r][col + 2] = v.z; T[r][col + 3] = v.w;
    }
    __syncthreads();
    unsigned short* out = WT + (size_t)z * 1024 * 1024;
#pragma unroll
    for (int i = 0; i < 2; i++) {
        int c = tid + i * 256;
        int nr = c >> 3, koff = (c & 7) * 8;
        union { unsigned short us[8]; uint4 v; } pk;
#pragma unroll
        for (int j = 0; j < 8; j++) pk.us[j] = f2bf(T[koff + j][nr]);
        *(uint4*)(out + (size_t)(n0 + nr) * 1024 + k0 + koff) = pk.v;
    }
}

// ---------------- QKV GEMM: [4096][1024] x WT^T per z; BK=64, static dbuf, 1 barrier ----
// Flat grid 768, XCD-swizzled decode (8 n-blocks of a (z,m) tile on one XCD).
// K-loop unrolled x2 over static buffer pairs: each step = ONE barrier (publishes the
// buffer staged during the previous step's compute) -> issue next stage -> compute.
// Staging latency hides under 32 MFMAs. 64KB LDS, 2 blocks/CU.
__global__ __launch_bounds__(256) void gemm_qkv(const unsigned short* __restrict__ A,
                                                const unsigned short* __restrict__ WTall,
                                                unsigned short* __restrict__ outq,
                                                unsigned short* __restrict__ Vp) {
    __shared__ unsigned short As0[128 * 64];
    __shared__ unsigned short Bs0[128 * 64];
    __shared__ unsigned short As1[128 * 64];
    __shared__ unsigned short Bs1[128 * 64];
    const int tid = threadIdx.x;
    const int w = tid >> 6, lane = tid & 63, quad = lane >> 4, ln = lane & 15;

    const int blk = blockIdx.x;
    const int n0 = ((blk >> 3) & 7) * 128;
    const int g  = ((blk >> 6) << 3) | (blk & 7);   // 0..95 = z*32+m
    const int z  = g >> 5;
    const int m0 = (g & 31) * 128;

    const unsigned short* BT = WTall + (size_t)z * (1024 * 1024);
    const float scl = (z == 0) ? 0.180336878f : 1.0f;
    const bool swp = (z < 2);

    const int lr8 = lane >> 3;                      // row within 8-row staging group
    const int lc8 = ((lane & 7) ^ lr8) * 8;         // XOR-swizzled source chunk (elems)
    const int fsw = (quad ^ (ln & 7)) * 8;          // swizzled frag-read chunk (elems)

    const f32x4 z4 = {0.f, 0.f, 0.f, 0.f};
    f32x4 acc[4][4];
#pragma unroll
    for (int i = 0; i < 4; i++)
#pragma unroll
        for (int j = 0; j < 4; j++) acc[i][j] = z4;

    const int wm = (w & 1) * 64, wn = (w >> 1) * 64;
    const int Rb = w * 32;                          // staging row base for this wave

#define QKV_STAGE(Ad, Bd, kk)                                                              \
    {                                                                                      \
        _Pragma("unroll")                                                                  \
        for (int s = 0; s < 4; s++) {                                                      \
            gld16(Ad + (Rb + s * 8) * 64, A  + (size_t)(m0 + Rb + s * 8 + lr8) * 1024 + (kk) + lc8); \
            gld16(Bd + (Rb + s * 8) * 64, BT + (size_t)(n0 + Rb + s * 8 + lr8) * 1024 + (kk) + lc8); \
        }                                                                                  \
    }

#define QKV_COMPUTE(Ad, Bd)                                                                \
    {                                                                                      \
        _Pragma("unroll")                                                                  \
        for (int ks = 0; ks < 2; ks++) {                                                   \
            const int co = fsw ^ (ks * 32);                                                \
            bf16x8 af[4], bfr[4];                                                          \
            _Pragma("unroll")                                                              \
            for (int t = 0; t < 4; t++)                                                    \
                af[t] = *(const bf16x8*)&Ad[(wm + t * 16 + ln) * 64 + co];                 \
            _Pragma("unroll")                                                              \
            for (int t = 0; t < 4; t++)                                                    \
                bfr[t] = *(const bf16x8*)&Bd[(wn + t * 16 + ln) * 64 + co];                \
            if (swp) {                                                                     \
                _Pragma("unroll")                                                          \
                for (int tm = 0; tm < 4; tm++)                                             \
                    _Pragma("unroll")                                                      \
                    for (int tn = 0; tn < 4; tn++)                                         \
                        acc[tm][tn] = __builtin_amdgcn_mfma_f32_16x16x32_bf16(             \
                            bfr[tn], af[tm], acc[tm][tn], 0, 0, 0);                        \
            } else {                                                                       \
                _Pragma("unroll")                                                          \
                for (int tm = 0; tm < 4; tm++)                                             \
                    _Pragma("unroll")                                                      \
                    for (int tn = 0; tn < 4; tn++)                                         \
                        acc[tm][tn] = __builtin_amdgcn_mfma_f32_16x16x32_bf16(             \
                            af[tm], bfr[tn], acc[tm][tn], 0, 0, 0);                        \
            }                                                                              \
        }                                                                                  \
    }

    QKV_STAGE(As0, Bs0, 0);
    for (int k0 = 0; k0 < 1024; k0 += 128) {
        __syncthreads();                          // publishes buf0 (drains its staging)
        if (k0 + 64 < 1024) QKV_STAGE(As1, Bs1, k0 + 64);
        QKV_COMPUTE(As0, Bs0);
        __syncthreads();                          // publishes buf1
        if (k0 + 128 < 1024) QKV_STAGE(As0, Bs0, k0 + 128);
        if (k0 + 64 < 1024) QKV_COMPUTE(As1, Bs1);
    }
#undef QKV_STAGE
#undef QKV_COMPUTE

    if (swp) {
        // acc[tm][tn] = D^T block: lane ln -> s-row, regs -> 4 consecutive d
#pragma unroll
        for (int tm = 0; tm < 4; tm++)
#pragma unroll
            for (int tn = 0; tn < 4; tn++) {
                int mg = m0 + wm + tm * 16 + ln;            // s row (global among 4096)
                int nb = n0 + wn + tn * 16 + quad * 4;      // d col base
                int b = mg >> 11, s = mg & 2047, h = nb >> 6, dd = nb & 63;
                ushort4 o;
                o.x = f2bf(acc[tm][tn][0] * scl);
                o.y = f2bf(acc[tm][tn][1] * scl);
                o.z = f2bf(acc[tm][tn][2] * scl);
                o.w = f2bf(acc[tm][tn][3] * scl);
                size_t zoff = (size_t)z * (4096 * 1024);
                *(ushort4*)(outq + zoff + (((size_t)(b * 16 + h) * 2048 + s) << 6) + dd) = o;
            }
    } else {
        // V: normal D block: lane ln -> d, regs -> 4 consecutive s = one Vp permute group
#pragma unroll
        for (int tm = 0; tm < 4; tm++)
#pragma unroll
            for (int tn = 0; tn < 4; tn++) {
                int mg = m0 + wm + tm * 16 + quad * 4;      // s base (r spans 4)
                int ng = n0 + wn + tn * 16 + ln;            // d
                int b = mg >> 11, h = ng >> 6, dd = ng & 63;
                int sblk = (mg & 2047) & ~63;
                int cb = tm >> 1, t16 = tm & 1;
                int pp = cb * 32 + quad * 8 + t16 * 4;
                ushort4 o;
                o.x = f2bf(acc[tm][tn][0]);
                o.y = f2bf(acc[tm][tn][1]);
                o.z = f2bf(acc[tm][tn][2]);
                o.w = f2bf(acc[tm][tn][3]);
                *(ushort4*)(Vp + ((size_t)(b * 16 + h) * 64 + dd) * 2048 + sblk + pp) = o;
            }
    }
}

// ---------------- out-proj GEMM: out[4096][1024] = AO @ WoT^T, 128x128, static dbuf ----
__global__ __launch_bounds__(256) void gemm_o(const unsigned short* __restrict__ A,
                                              const unsigned short* __restrict__ BT,
                                              float* __restrict__ outf) {
    __shared__ unsigned short As0[128 * 64];
    __shared__ unsigned short Bs0[128 * 64];
    __shared__ unsigned short As1[128 * 64];
    __shared__ unsigned short Bs1[128 * 64];
    const int tid = threadIdx.x;
    const int w = tid >> 6, lane = tid & 63, quad = lane >> 4, ln = lane & 15;

    const int blk = blockIdx.x;
    const int n0 = ((blk >> 3) & 7) * 128;
    const int m0 = (((blk >> 6) << 3) | (blk & 7)) * 128;   // 0..31 tiles

    const int lr8 = lane >> 3;
    const int lc8 = ((lane & 7) ^ lr8) * 8;
    const int fsw = (quad ^ (ln & 7)) * 8;

    const f32x4 z4 = {0.f, 0.f, 0.f, 0.f};
    f32x4 acc[4][4];
#pragma unroll
    for (int i = 0; i < 4; i++)
#pragma unroll
        for (int j = 0; j < 4; j++) acc[i][j] = z4;

    const int wm = (w & 1) * 64, wn = (w >> 1) * 64;
    const int Rb = w * 32;

#define O_STAGE(Ad, Bd, kk)                                                                \
    {                                                                                      \
        _Pragma("unroll")                                                                  \
        for (int s = 0; s < 4; s++) {                                                      \
            gld16(Ad + (Rb + s * 8) * 64, A  + (size_t)(m0 + Rb + s * 8 + lr8) * 1024 + (kk) + lc8); \
            gld16(Bd + (Rb + s * 8) * 64, BT + (size_t)(n0 + Rb + s * 8 + lr8) * 1024 + (kk) + lc8); \
        }                                                                                  \
    }

#define O_COMPUTE(Ad, Bd)                                                                  \
    {                                                                                      \
        _Pragma("unroll")                                                                  \
        for (int ks = 0; ks < 2; ks++) {                                                   \
            const int co = fsw ^ (ks * 32);                                                \
            bf16x8 af[4], bfr[4];                                                          \
            _Pragma("unroll")                                                              \
            for (int t = 0; t < 4; t++)                                                    \
                af[t] = *(const bf16x8*)&Ad[(wm + t * 16 + ln) * 64 + co];                 \
            _Pragma("unroll")                                                              \
            for (int t = 0; t < 4; t++)                                                    \
                bfr[t] = *(const bf16x8*)&Bd[(wn + t * 16 + ln) * 64 + co];                \
            _Pragma("unroll")                                                              \
            for (int tm = 0; tm < 4; tm++)                                                 \
                _Pragma("unroll")                                                          \
                for (int tn = 0; tn < 4; tn++)                                             \
                    acc[tm][tn] = __builtin_amdgcn_mfma_f32_16x16x32_bf16(                 \
                        bfr[tn], af[tm], acc[tm][tn], 0, 0, 0);                            \
        }                                                                                  \
    }

    O_STAGE(As0, Bs0, 0);
    for (int k0 = 0; k0 < 1024; k0 += 128) {
        __syncthreads();
        if (k0 + 64 < 1024) O_STAGE(As1, Bs1, k0 + 64);
        O_COMPUTE(As0, Bs0);
        __syncthreads();
        if (k0 + 128 < 1024) O_STAGE(As0, Bs0, k0 + 128);
        if (k0 + 64 < 1024) O_COMPUTE(As1, Bs1);
    }
#undef O_STAGE
#undef O_COMPUTE

    // D^T blocks: lane ln -> output row, reg quad -> 4 consecutive cols -> float4 stores
#pragma unroll
    for (int tm = 0; tm < 4; tm++)
#pragma unroll
        for (int tn = 0; tn < 4; tn++) {
            int mg = m0 + wm + tm * 16 + ln;
            int nb = n0 + wn + tn * 16 + quad * 4;
            *(f32x4*)(outf + (size_t)mg * 1024 + nb) = acc[tm][tn];
        }
}

// ---------------- flash attention (split-K heavy tiles, 8 waves, grid 768) --------------
// Slot decode: bh = blk&31, s = blk>>5 (0..23).
//   s<8:    light q-tile qi=s, full k range [0,(qi+1)*128), normalize, write AO.
//   s>=8:   heavy q-tile qi=15-((s-8)&7), half=(s-8)>>3; k in [0,mid) or [mid,(qi+1)*128),
//           mid=(qi+1)*64; write fp32 partial O + lsum to workspace (merged later).
// CU triple (s, s+8, s+16) = light(2s+2) + 2x(16-s) tiles = 34 for every CU; max serial
// chain 16 tiles. Dbuf staging, ONE barrier per tile; XOR chunk swizzle; S^T = K Q^T;
// fixed-shift exp2 (disjoint-k partials addable: O_tot = O0+O1, l_tot = l0+l1).
__global__ __launch_bounds__(512, 4) void flash(const unsigned short* __restrict__ Qb,
                                                const unsigned short* __restrict__ Kb,
                                                const unsigned short* __restrict__ Vpb,
                                                unsigned short* __restrict__ AO,
                                                float* __restrict__ Ph0,
                                                float* __restrict__ Ph1,
                                                float* __restrict__ Lb) {
    __shared__ __align__(16) unsigned short Ks[2][64 * 64];
    __shared__ __align__(16) unsigned short Vs[2][64 * 64];
    const int tid = threadIdx.x, w = tid >> 6, lane = tid & 63;
    const int qd = lane >> 4, ln = lane & 15;
    const int lr = lane >> 3;                  // row-within-8 for staging
    const int lchunk = (lane & 7) ^ lr;        // swizzled source 16B-chunk
    const int psw = (qd ^ (ln & 7)) * 8;       // swizzled read chunk offset (elems)

    const int blk = blockIdx.x;
    const int bh = blk & 31;
    const int s  = blk >> 5;                   // 0..23
    int qi, kstart, kend, half;
    bool heavy;
    if (s < 8) {
        qi = s; kstart = 0; kend = (qi + 1) * 128; half = 0; heavy = false;
    } else {
        int t = s - 8; half = t >> 3; qi = 15 - (t & 7); heavy = true;
        int mid = (qi + 1) * 64;
        kstart = half ? mid : 0;
        kend   = half ? (qi + 1) * 128 : mid;
    }
    const int qt0 = qi * 128;

    const unsigned short* Kg = Kb  + (size_t)bh * 2048 * 64;
    const unsigned short* Vg = Vpb + (size_t)bh * 64 * 2048;

    // Q fragment (B-operand of S^T MFMA): lane ln holds Q[qt0+w*16+ln][qd*8+j]
    bf16x8 aq[2];
    {
        const unsigned short* Qrow = Qb + ((size_t)bh * 2048 + qt0 + w * 16 + ln) * 64 + qd * 8;
        aq[0] = *(const bf16x8*)(Qrow);
        aq[1] = *(const bf16x8*)(Qrow + 32);
    }

    const f32x4 z4 = {0.f, 0.f, 0.f, 0.f};
    f32x4 Oc[4];
#pragma unroll
    for (int td = 0; td < 4; td++) Oc[td] = z4;
    float lsum = 0.f;

    const int qrow = qt0 + w * 16 + ln;   // lane's q row (S^T: q indexed by ln)
    const int qmin = qt0 + w * 16;
    const int qmax = qmin + 15;

    // stage(buf, kk): wave w fills K rows [w*8,w*8+8) and Vp d-rows [w*8,w*8+8)
#define FLASH_STAGE(buf, kk)                                                          \
    {                                                                                 \
        const unsigned short* kg = Kg + (size_t)((kk) + w * 8 + lr) * 64 + lchunk * 8; \
        gld16(&Ks[buf][(w * 8) * 64], kg);                                            \
        const unsigned short* vg = Vg + (size_t)(w * 8 + lr) * 2048 + (kk) + lchunk * 8; \
        gld16(&Vs[buf][(w * 8) * 64], vg);                                            \
    }

    FLASH_STAGE(0, kstart);
    int cur = 0;

    for (int k0 = kstart; k0 < kend; k0 += 64) {
        __syncthreads();                    // publishes buf cur (drains staging vmcnt)
        if (k0 + 64 < kend) FLASH_STAGE(cur ^ 1, k0 + 64);

        if (k0 <= qmax) {                   // wave-uniform: tile contributes for this wave
            // S^T = K Q^T : output lane (qd,ln) reg r = S[q=ln][kk = t*16 + qd*4 + r]
            f32x4 sc[4];
#pragma unroll
            for (int t = 0; t < 4; t++) {
                sc[t] = z4;
                if (k0 + t * 16 <= qmax) {
                    int off = (t * 16 + ln) * 64 + psw;
                    bf16x8 bk0 = *(const bf16x8*)&Ks[cur][off];
                    bf16x8 bk1 = *(const bf16x8*)&Ks[cur][off ^ 32];
                    sc[t] = __builtin_amdgcn_mfma_f32_16x16x32_bf16(bk0, aq[0], sc[t], 0, 0, 0);
                    sc[t] = __builtin_amdgcn_mfma_f32_16x16x32_bf16(bk1, aq[1], sc[t], 0, 0, 0);
                }
            }

            // P = exp2(S) (fixed shift), causal mask only in crossing band; pack bf16x2
            unsigned int pk[4][2];
#pragma unroll
            for (int t = 0; t < 4; t++) {
                if (k0 + t * 16 > qmax) { pk[t][0] = 0u; pk[t][1] = 0u; continue; }
                float e[4];
#pragma unroll
                for (int r2 = 0; r2 < 4; r2++) e[r2] = __builtin_amdgcn_exp2f(sc[t][r2]);
                if (k0 + t * 16 + 15 > qmin) {
#pragma unroll
                    for (int r2 = 0; r2 < 4; r2++)
                        if (k0 + t * 16 + qd * 4 + r2 > qrow) e[r2] = 0.f;
                }
                lsum += (e[0] + e[1]) + (e[2] + e[3]);
                pk[t][0] = (unsigned int)f2bf(e[0]) | ((unsigned int)f2bf(e[1]) << 16);
                pk[t][1] = (unsigned int)f2bf(e[2]) | ((unsigned int)f2bf(e[3]) << 16);
            }

            // O^T += V^T P^T under permuted contraction: B-frag(c) = own regs pk[2c..2c+1]
            union { unsigned int u[4]; bf16x8 v; } apu0, apu1;
            apu0.u[0] = pk[0][0]; apu0.u[1] = pk[0][1]; apu0.u[2] = pk[1][0]; apu0.u[3] = pk[1][1];
            apu1.u[0] = pk[2][0]; apu1.u[1] = pk[2][1]; apu1.u[2] = pk[3][0]; apu1.u[3] = pk[3][1];
#pragma unroll
            for (int td = 0; td < 4; td++) {
                int voff = (td * 16 + ln) * 64 + psw;
                bf16x8 av0 = *(const bf16x8*)&Vs[cur][voff];
                bf16x8 av1 = *(const bf16x8*)&Vs[cur][voff ^ 32];
                Oc[td] = __builtin_amdgcn_mfma_f32_16x16x32_bf16(av0, apu0.v, Oc[td], 0, 0, 0);
                Oc[td] = __builtin_amdgcn_mfma_f32_16x16x32_bf16(av1, apu1.v, Oc[td], 0, 0, 0);
            }
        }
        cur ^= 1;
    }
#undef FLASH_STAGE

    // row-sum butterfly across quads (lanes ln, ln+16, ln+32, ln+48 hold partials)
    lsum += __shfl_xor(lsum, 16);
    lsum += __shfl_xor(lsum, 32);

    if (!heavy) {
        const float inv = 1.0f / lsum;
        // O^T output: lane (qd,ln) reg (td,r) = O[q=ln][d = td*16 + qd*4 + r]
        const int bz = bh >> 4, h = bh & 15;
        const int rowg = qt0 + w * 16 + ln;
        unsigned short* aorow = AO + ((size_t)(bz * 2048 + rowg) << 10) + h * 64 + qd * 4;
#pragma unroll
        for (int td = 0; td < 4; td++) {
            ushort4 o;
            o.x = f2bf(Oc[td][0] * inv);
            o.y = f2bf(Oc[td][1] * inv);
            o.z = f2bf(Oc[td][2] * inv);
            o.w = f2bf(Oc[td][3] * inv);
            *(ushort4*)(aorow + td * 16) = o;
        }
    } else {
        // fp32 partial: P[(bh*8+qi-8)*128 + q][64]; lsum -> Lb[half*32768 + prow]
        float* P = half ? Ph1 : Ph0;
        const int prow = ((bh * 8 + (qi - 8)) * 128) + w * 16 + ln;
        float* Pr = P + (size_t)prow * 64 + qd * 4;
#pragma unroll
        for (int td = 0; td < 4; td++)
            *(f32x4*)(Pr + td * 16) = Oc[td];
        if (qd == 0) Lb[half * 32768 + prow] = lsum;
    }
}

// ---------------- merge heavy split-K partials -> AO ------------------------------------
// 32768 rows x 64 d; thread handles 8 d. O = (P0+P1)/(l0+l1), bf16, into AO heavy rows.
__global__ __launch_bounds__(256) void merge(const float* __restrict__ P0,
                                             const float* __restrict__ P1,
                                             const float* __restrict__ Lb,
                                             unsigned short* __restrict__ AO) {
    const int idx = blockIdx.x * 256 + threadIdx.x;   // 0..262143
    const int d0 = (idx & 7) * 8;
    const int row = idx >> 3;                          // (bh*8+qi8)*128 + q
    const float inv = 1.0f / (Lb[row] + Lb[32768 + row]);
    const float* a = P0 + (size_t)row * 64 + d0;
    const float* b = P1 + (size_t)row * 64 + d0;
    f32x4 x0 = *(const f32x4*)a, x1 = *(const f32x4*)(a + 4);
    f32x4 y0 = *(const f32x4*)b, y1 = *(const f32x4*)(b + 4);
    union { unsigned short us[8]; uint4 v; } pk;
#pragma unroll
    for (int j = 0; j < 4; j++) {
        pk.us[j]     = f2bf((x0[j] + y0[j]) * inv);
        pk.us[j + 4] = f2bf((x1[j] + y1[j]) * inv);
    }
    const int bh = row >> 10, qi8 = (row >> 7) & 7, q = row & 127;
    const int bz = bh >> 4, h = bh & 15;
    const int rowg = (qi8 + 8) * 128 + q;
    *(uint4*)(AO + ((size_t)(bz * 2048 + rowg) << 10) + h * 64 + d0) = pk.v;
}

extern "C" void kernel_launch(void* const* d_in, const int* in_sizes, int n_in,
                              void* d_out, int out_size, void* d_ws, size_t ws_size,
                              hipStream_t stream) {
    const float* x  = (const float*)d_in[0];
    const float* Wq = (const float*)d_in[1];
    const float* Wk = (const float*)d_in[2];
    const float* Wv = (const float*)d_in[3];
    const float* Wo = (const float*)d_in[4];
    float* out = (float*)d_out;

    unsigned short* xb  = (unsigned short*)d_ws;           // 4096*1024
    unsigned short* WT  = xb  + (size_t)4096 * 1024;       // 4*1024*1024
    unsigned short* Qb  = WT  + (size_t)4 * 1024 * 1024;   // Q,K contiguous ([B][H][S][64])
    unsigned short* Kb  = Qb  + (size_t)4096 * 1024;
    unsigned short* Vb  = Kb  + (size_t)4096 * 1024;       // dead slot -> half0 partials
    unsigned short* Vpb = Vb  + (size_t)4096 * 1024;       // Vp [B][H][64][S] permuted
    unsigned short* AO  = Vpb + (size_t)4096 * 1024;

    float* Ph0 = (float*)Vb;   // 8 MB: heavy half0 fp32 partial O (exactly 2M floats)
    float* Ph1 = (float*)xb;   // 8 MB: heavy half1 (xb dead after gemm_qkv)
    float* Lb  = (float*)WT;   // 256 KB: lsum partials (Wq^T region dead after gemm_qkv)

    castx<<<4096, 256, 0, stream>>>(x, xb);
    wtrans<<<dim3(16, 16, 4), 256, 0, stream>>>(Wq, Wk, Wv, Wo, WT);
    gemm_qkv<<<dim3(768), 256, 0, stream>>>(xb, WT, Qb, Vpb);
    flash<<<dim3(768), 512, 0, stream>>>(Qb, Kb, Vpb, AO, Ph0, Ph1, Lb);
    merge<<<dim3(1024), 256, 0, stream>>>(Ph0, Ph1, Lb, AO);
    gemm_o<<<dim3(256), 256, 0, stream>>>(AO, WT + (size_t)3 * 1024 * 1024, out);
}